// Round 1
// baseline (489.222 us; speedup 1.0000x reference)
//
#include <hip/hip_runtime.h>

#define BATCH 16
#define CIN 512
#define NPIX 4096

typedef __attribute__((ext_vector_type(8))) short bf16x8;
typedef __attribute__((ext_vector_type(4))) float f32x4;

#define MFMA(a,b,c) __builtin_amdgcn_mfma_f32_16x16x32_bf16((a),(b),(c),0,0,0)

union PK { short s[8]; bf16x8 v; };

__device__ __forceinline__ unsigned short bf16_rne(float f){
  unsigned u = __float_as_uint(f);
  return (unsigned short)((u + 0x7fffu + ((u >> 16) & 1u)) >> 16);
}
__device__ __forceinline__ unsigned short f32_hi(float f){
  return (unsigned short)(__float_as_uint(f) >> 16);
}
__device__ __forceinline__ void f32_split(float f, short &h, short &l){
  unsigned u = __float_as_uint(f);
  h = (short)(u >> 16);
  float fh = __uint_as_float(u & 0xffff0000u);
  l = (short)(__float_as_uint(f - fh) >> 16);
}

// Swizzled LDS offsets (ushort units). Chunk = 8 shorts = 16B.
// Generic: row stride `stride` shorts (stride*2 bytes must be 0 mod 128 for full effect)
__device__ __forceinline__ int offBig(int row, int k, int stride){
  int s = k >> 3;
  s = (s & ~7) | ((s ^ row) & 7);
  return row*stride + s*8 + (k & 7);
}
// 64-short (128B) rows, full 64 shorts of data
__device__ __forceinline__ int off128(int row, int k){
  int s = k >> 3;
  s = (s & ~7) | ((s ^ row) & 7);
  return row*64 + s*8 + (k & 7);
}
// 64-short (128B) rows, 32 shorts of data placed across 8 slots
__device__ __forceinline__ int off64in128(int row, int k){
  int s = (((k >> 3) ^ row) & 3) | (row & 4);
  return row*64 + s*8 + (k & 7);
}

// ---------------- weight convert ----------------
// WG: interleaved gate weights [512][512] bf16 (row 2o = Wq[o], 2o+1 = Wk[o])
// WPh/WPl: proj weights split [640][512] (rows 0-511 Wv, 512-575 Ws, 576-639 We)
// BG [512] interleaved biases, BP [640]
__global__ __launch_bounds__(256)
void k_convw(const float* __restrict__ Wq, const float* __restrict__ bq,
             const float* __restrict__ Wk, const float* __restrict__ bk,
             const float* __restrict__ Wv, const float* __restrict__ bv,
             const float* __restrict__ Wsq, const float* __restrict__ bsq,
             const float* __restrict__ We, const float* __restrict__ be,
             short* __restrict__ WG, short* __restrict__ WPh, short* __restrict__ WPl,
             float* __restrict__ BG, float* __restrict__ BP){
  int t = blockIdx.x*256 + threadIdx.x;
  if (t < 512*512){
    int r = t >> 9, c = t & 511, o = r >> 1;
    float v = (r & 1) ? Wk[o*512 + c] : Wq[o*512 + c];
    WG[t] = (short)bf16_rne(v);
  }
  if (t < 640*512){
    int r = t >> 9, c = t & 511;
    float v = (r < 512) ? Wv[r*512 + c] : (r < 576) ? Wsq[(r-512)*512 + c] : We[(r-576)*512 + c];
    short h, l; f32_split(v, h, l);
    WPh[t] = h; WPl[t] = l;
  }
  if (t < 512) BG[t] = (t & 1) ? bk[t>>1] : bq[t>>1];
  if (t < 640) BP[t] = (t < 512) ? bv[t] : (t < 576) ? bsq[t-512] : be[t-576];
}

// ---------------- gate ----------------
// grid (64 ntiles, 16 b), 512 threads (8 waves). Computes gate[b][n].
__global__ __launch_bounds__(512)
void k_gate(const float* __restrict__ x, const short* __restrict__ WG,
            const float* __restrict__ BG, float* __restrict__ GATE){
  __shared__ __align__(16) short XS[64*512];  // [n][c] bf16-hi, swizzled, 64KB
  __shared__ __align__(16) short WS[512*64];  // [o][32 data in 64-pad], 64KB (reused for reduce)
  int b = blockIdx.y, n0 = blockIdx.x*64;
  int tid = threadIdx.x, w = tid>>6, lane = tid&63;
  int lr = lane & 15, lk = (lane >> 4) << 3;
  // stage XS: thread = channel c, transpose-write 64 n values
  {
    const float* xp = x + ((size_t)b*CIN + tid)*NPIX + n0;
    for (int i=0;i<64;i+=4){
      float4 v = *(const float4*)(xp + i);
      float vv[4] = {v.x, v.y, v.z, v.w};
      #pragma unroll
      for (int u=0;u<4;u++)
        XS[offBig(i+u, tid, 512)] = (short)f32_hi(vv[u]);
    }
  }
  f32x4 acc[4][4] = {};
  for (int kt=0; kt<16; kt++){
    __syncthreads();
    { // stage W k-tile [512][32]
      const short* wp = WG + (size_t)tid*512 + kt*32;
      #pragma unroll
      for (int j=0;j<4;j++)
        *(bf16x8*)&WS[off64in128(tid, j*8)] = *(const bf16x8*)(wp + j*8);
    }
    __syncthreads();
    bf16x8 bb[4];
    #pragma unroll
    for (int j=0;j<4;j++)
      bb[j] = *(const bf16x8*)&XS[offBig(j*16 + lr, kt*32 + lk, 512)];
    #pragma unroll
    for (int r=0;r<4;r++){
      bf16x8 a = *(const bf16x8*)&WS[off64in128(w*64 + r*16 + lr, lk)];
      #pragma unroll
      for (int j=0;j<4;j++)
        acc[r][j] = MFMA(a, bb[j], acc[r][j]);
    }
  }
  // rows interleaved: pairs (Q,K) in adjacent accumulator regs
  float p[4] = {0.f,0.f,0.f,0.f};
  int rq = (lane>>4)<<2;
  #pragma unroll
  for (int r=0;r<4;r++){
    f32x4 bg = *(const f32x4*)&BG[w*64 + r*16 + rq];
    #pragma unroll
    for (int j=0;j<4;j++){
      f32x4 a4 = acc[r][j];
      p[j] += (a4[0]+bg[0])*(a4[1]+bg[1]) + (a4[2]+bg[2])*(a4[3]+bg[3]);
    }
  }
  #pragma unroll
  for (int j=0;j<4;j++){
    p[j] += __shfl_xor(p[j], 16);
    p[j] += __shfl_xor(p[j], 32);
  }
  __syncthreads();             // done with WS tiles; reuse as reduce buffer
  float* QKf = (float*)WS;     // [8][64]
  if (lane < 16){
    #pragma unroll
    for (int j=0;j<4;j++) QKf[w*64 + j*16 + lane] = p[j];
  }
  __syncthreads();
  if (tid < 64){
    float s = 0.f;
    #pragma unroll
    for (int ww=0; ww<8; ww++) s += QKf[ww*64 + tid];
    GATE[(size_t)b*NPIX + n0 + tid] = 1.f / (1.f + __expf(-s * (1.f/256.f)));
  }
}

// ---------------- projections (V*gate, Qs, Ke^T) ----------------
// grid (64 nt, 5 ct, 16 b), 256 threads (4 waves). Split-bf16 except Ke rows.
__global__ __launch_bounds__(256)
void k_proj(const float* __restrict__ x, const short* __restrict__ WPh, const short* __restrict__ WPl,
            const float* __restrict__ BP, const float* __restrict__ GATE,
            float* __restrict__ VDW, float* __restrict__ QSB, float* __restrict__ KET){
  __shared__ __align__(16) short WH[128*64], WL[128*64]; // [row][32 in 64]
  __shared__ __align__(16) short XH[64*64],  XL[64*64];  // [n][32 in 64]
  int nt = blockIdx.x, ct = blockIdx.y, b = blockIdx.z;
  int n0 = nt*64;
  int tid = threadIdx.x, w = tid>>6, lane = tid&63;
  int lr = lane&15, lk = (lane>>4)<<3;
  bool split = (ct < 4) || (w < 2);
  f32x4 acc[2][4] = {};
  for (int kt=0; kt<16; kt++){
    __syncthreads();
    { // stage W [128][32] hi+lo
      int r = tid >> 1, half = tid & 1;
      const short* ph = WPh + (size_t)(ct*128 + r)*512 + kt*32 + half*16;
      const short* pl = WPl + (size_t)(ct*128 + r)*512 + kt*32 + half*16;
      *(bf16x8*)&WH[off64in128(r, half*16 + 0)] = *(const bf16x8*)(ph);
      *(bf16x8*)&WH[off64in128(r, half*16 + 8)] = *(const bf16x8*)(ph + 8);
      *(bf16x8*)&WL[off64in128(r, half*16 + 0)] = *(const bf16x8*)(pl);
      *(bf16x8*)&WL[off64in128(r, half*16 + 8)] = *(const bf16x8*)(pl + 8);
    }
    { // stage X [64 n][32 c] hi+lo (transpose from x)
      int c = tid >> 3, nb = (tid & 7)*8;
      const float* xp = x + ((size_t)b*CIN + kt*32 + c)*NPIX + n0 + nb;
      float4 v0 = *(const float4*)(xp);
      float4 v1 = *(const float4*)(xp + 4);
      float vv[8] = {v0.x,v0.y,v0.z,v0.w,v1.x,v1.y,v1.z,v1.w};
      #pragma unroll
      for (int u=0;u<8;u++){
        short h,l; f32_split(vv[u], h, l);
        XH[off64in128(nb+u, c)] = h;
        XL[off64in128(nb+u, c)] = l;
      }
    }
    __syncthreads();
    bf16x8 bh[4], bl[4];
    #pragma unroll
    for (int j=0;j<4;j++){
      bh[j] = *(const bf16x8*)&XH[off64in128(j*16+lr, lk)];
      bl[j] = *(const bf16x8*)&XL[off64in128(j*16+lr, lk)];
    }
    #pragma unroll
    for (int r=0;r<2;r++){
      bf16x8 ah = *(const bf16x8*)&WH[off64in128(w*32 + r*16 + lr, lk)];
      #pragma unroll
      for (int j=0;j<4;j++)
        acc[r][j] = MFMA(ah, bh[j], acc[r][j]);
      if (split){
        bf16x8 al = *(const bf16x8*)&WL[off64in128(w*32 + r*16 + lr, lk)];
        #pragma unroll
        for (int j=0;j<4;j++){
          acc[r][j] = MFMA(ah, bl[j], acc[r][j]);
          acc[r][j] = MFMA(al, bh[j], acc[r][j]);
        }
      }
    }
  }
  int rq = (lane>>4)<<2;
  #pragma unroll
  for (int r=0;r<2;r++){
    int rowl = ct*128 + w*32 + r*16 + rq;
    f32x4 bp = *(const f32x4*)&BP[rowl];
    #pragma unroll
    for (int j=0;j<4;j++){
      int col = n0 + j*16 + (lane&15);
      if (ct < 4){
        float g = GATE[(size_t)b*NPIX + col];
        #pragma unroll
        for (int q=0;q<4;q++)
          VDW[(((size_t)b*512) + rowl + q)*NPIX + col] = (acc[r][j][q] + bp[q]) * g;
      } else if (w < 2){
        #pragma unroll
        for (int q=0;q<4;q++)
          QSB[(((size_t)b*64) + (rowl - 512 + q))*NPIX + col] = acc[r][j][q] + bp[q];
      } else {
        f32x4 v4;
        #pragma unroll
        for (int q=0;q<4;q++) v4[q] = acc[r][j][q] + bp[q];
        *(f32x4*)&KET[((size_t)b*NPIX + col)*64 + (rowl - 576)] = v4;
      }
    }
  }
}

// ---------------- energy: EN[b][512][64] += V_dw @ Qs^T (split-bf16) ----------------
// grid (4 kslab, 4 ct, 16 b), 256 threads
__global__ __launch_bounds__(256)
void k_energy(const float* __restrict__ VDW, const float* __restrict__ QSB,
              float* __restrict__ EN){
  __shared__ __align__(16) short VH[128*64], VL[128*64]; // [c][64 n]
  __shared__ __align__(16) short QH[64*64],  QL[64*64];  // [d][64 n]
  int ks = blockIdx.x, ct = blockIdx.y, b = blockIdx.z;
  int tid = threadIdx.x, w = tid>>6, lane = tid&63;
  int lr = lane&15, lk = (lane>>4)<<3;
  f32x4 acc[2][4] = {};
  for (int it=0; it<16; it++){
    int nb = ks*1024 + it*64;
    __syncthreads();
    { // stage V tile [128][64]
      int r = tid>>1, half = tid&1;
      const float* vp = VDW + (((size_t)b*512) + ct*128 + r)*NPIX + nb + half*32;
      #pragma unroll
      for (int u=0;u<32;u+=8){
        float4 a0 = *(const float4*)(vp+u);
        float4 a1 = *(const float4*)(vp+u+4);
        float vv[8] = {a0.x,a0.y,a0.z,a0.w,a1.x,a1.y,a1.z,a1.w};
        PK ph, pl;
        #pragma unroll
        for (int z=0;z<8;z++){ short h,l; f32_split(vv[z],h,l); ph.s[z]=h; pl.s[z]=l; }
        *(bf16x8*)&VH[off128(r, half*32+u)] = ph.v;
        *(bf16x8*)&VL[off128(r, half*32+u)] = pl.v;
      }
    }
    { // stage Qs tile [64][64]
      int r = tid>>2, qq = (tid&3)*16;
      const float* qp = QSB + (((size_t)b*64) + r)*NPIX + nb + qq;
      #pragma unroll
      for (int u=0;u<16;u+=8){
        float4 a0 = *(const float4*)(qp+u);
        float4 a1 = *(const float4*)(qp+u+4);
        float vv[8] = {a0.x,a0.y,a0.z,a0.w,a1.x,a1.y,a1.z,a1.w};
        PK ph, pl;
        #pragma unroll
        for (int z=0;z<8;z++){ short h,l; f32_split(vv[z],h,l); ph.s[z]=h; pl.s[z]=l; }
        *(bf16x8*)&QH[off128(r, qq+u)] = ph.v;
        *(bf16x8*)&QL[off128(r, qq+u)] = pl.v;
      }
    }
    __syncthreads();
    #pragma unroll
    for (int k0=0;k0<64;k0+=32){
      bf16x8 bh[4], bl[4];
      #pragma unroll
      for (int j=0;j<4;j++){
        bh[j] = *(const bf16x8*)&QH[off128(j*16+lr, k0+lk)];
        bl[j] = *(const bf16x8*)&QL[off128(j*16+lr, k0+lk)];
      }
      #pragma unroll
      for (int r=0;r<2;r++){
        bf16x8 ah = *(const bf16x8*)&VH[off128(w*32 + r*16 + lr, k0+lk)];
        bf16x8 al = *(const bf16x8*)&VL[off128(w*32 + r*16 + lr, k0+lk)];
        #pragma unroll
        for (int j=0;j<4;j++){
          acc[r][j] = MFMA(ah, bh[j], acc[r][j]);
          acc[r][j] = MFMA(ah, bl[j], acc[r][j]);
          acc[r][j] = MFMA(al, bh[j], acc[r][j]);
        }
      }
    }
  }
  int rq = (lane>>4)<<2;
  #pragma unroll
  for (int r=0;r<2;r++)
    #pragma unroll
    for (int j=0;j<4;j++)
      #pragma unroll
      for (int q=0;q<4;q++){
        int row = ct*128 + w*32 + r*16 + rq + q;
        atomicAdd(&EN[((size_t)b*512 + row)*64 + j*16 + lr], acc[r][j][q]);
      }
}

// ---------------- softmax over d=64 ----------------
__global__ __launch_bounds__(256)
void k_softmax(const float* __restrict__ EN, short* __restrict__ ATT){
  int row = blockIdx.x*4 + (threadIdx.x>>6);
  int lane = threadIdx.x & 63;
  float v = EN[(size_t)row*64 + lane];
  float m = v;
  #pragma unroll
  for (int s=1;s<64;s<<=1) m = fmaxf(m, __shfl_xor(m, s));
  float e = __expf(v - m);
  float sum = e;
  #pragma unroll
  for (int s=1;s<64;s<<=1) sum += __shfl_xor(sum, s);
  ATT[(size_t)row*64 + lane] = (short)bf16_rne(e / sum);
}

// ---------------- out = x + attn @ Ke ----------------
// grid (64 nt, 16 b), 256 threads
__global__ __launch_bounds__(256)
void k_out(const float* __restrict__ x, const short* __restrict__ ATT,
           const float* __restrict__ KET, float* __restrict__ out){
  __shared__ __align__(16) short AT[512*64]; // [c][d]
  __shared__ __align__(16) short KT[64*64];  // [n][d]
  int nt = blockIdx.x, b = blockIdx.y;
  int n0 = nt*64;
  int tid = threadIdx.x, w = tid>>6, lane = tid&63;
  int lr = lane&15, lk = (lane>>4)<<3;
  for (int rr = tid; rr < 512; rr += 256){
    const short* ap = ATT + ((size_t)b*512 + rr)*64;
    #pragma unroll
    for (int u=0;u<64;u+=8)
      *(bf16x8*)&AT[off128(rr, u)] = *(const bf16x8*)(ap + u);
  }
  {
    int n = tid>>2, qq = (tid&3)*16;
    const float* kp = KET + ((size_t)b*NPIX + n0 + n)*64 + qq;
    #pragma unroll
    for (int u=0;u<16;u+=8){
      float4 a0 = *(const float4*)(kp+u);
      float4 a1 = *(const float4*)(kp+u+4);
      float vv[8] = {a0.x,a0.y,a0.z,a0.w,a1.x,a1.y,a1.z,a1.w};
      PK pk;
      #pragma unroll
      for (int z=0;z<8;z++) pk.s[z] = (short)bf16_rne(vv[z]);
      *(bf16x8*)&KT[off128(n, qq+u)] = pk.v;
    }
  }
  __syncthreads();
  f32x4 acc[8][4] = {};
  #pragma unroll
  for (int k0=0;k0<64;k0+=32){
    bf16x8 bfr[4];
    #pragma unroll
    for (int j=0;j<4;j++)
      bfr[j] = *(const bf16x8*)&KT[off128(j*16+lr, k0+lk)];
    #pragma unroll
    for (int rf=0;rf<8;rf++){
      bf16x8 a = *(const bf16x8*)&AT[off128(w*128 + rf*16 + lr, k0+lk)];
      #pragma unroll
      for (int j=0;j<4;j++)
        acc[rf][j] = MFMA(a, bfr[j], acc[rf][j]);
    }
  }
  int rq = (lane>>4)<<2;
  #pragma unroll
  for (int rf=0;rf<8;rf++)
    #pragma unroll
    for (int j=0;j<4;j++){
      int col = n0 + j*16 + lr;
      #pragma unroll
      for (int q=0;q<4;q++){
        int row = w*128 + rf*16 + rq + q;
        size_t idx = ((size_t)b*512 + row)*NPIX + col;
        out[idx] = x[idx] + acc[rf][j][q];
      }
    }
}

extern "C" void kernel_launch(void* const* d_in, const int* in_sizes, int n_in,
                              void* d_out, int out_size, void* d_ws, size_t ws_size,
                              hipStream_t stream){
  const float* x   = (const float*)d_in[0];
  const float* Wq  = (const float*)d_in[1];
  const float* bq  = (const float*)d_in[2];
  const float* Wk  = (const float*)d_in[3];
  const float* bk  = (const float*)d_in[4];
  const float* Wv  = (const float*)d_in[5];
  const float* bv  = (const float*)d_in[6];
  const float* Wsq = (const float*)d_in[7];
  const float* bsq = (const float*)d_in[8];
  const float* We  = (const float*)d_in[9];
  const float* be  = (const float*)d_in[10];
  float* out = (float*)d_out;

  char* wsb = (char*)d_ws;
  size_t off = 0;
  auto alloc = [&](size_t bytes)->void*{
    void* p = wsb + off; off += (bytes + 255) & ~(size_t)255; return p;
  };
  short* WG  = (short*)alloc((size_t)512*512*2);
  short* WPh = (short*)alloc((size_t)640*512*2);
  short* WPl = (short*)alloc((size_t)640*512*2);
  float* BG  = (float*)alloc(512*4);
  float* BP  = (float*)alloc(640*4);
  float* GATE= (float*)alloc((size_t)BATCH*NPIX*4);
  float* VDW = (float*)alloc((size_t)BATCH*512*NPIX*4);
  float* QSB = (float*)alloc((size_t)BATCH*64*NPIX*4);
  float* KET = (float*)alloc((size_t)BATCH*NPIX*64*4);
  float* EN  = (float*)alloc((size_t)BATCH*512*64*4);
  short* ATT = (short*)alloc((size_t)BATCH*512*64*2);

  hipMemsetAsync(EN, 0, (size_t)BATCH*512*64*4, stream);
  k_convw<<<1280, 256, 0, stream>>>(Wq,bq,Wk,bk,Wv,bv,Wsq,bsq,We,be, WG,WPh,WPl,BG,BP);
  k_gate<<<dim3(64,16), 512, 0, stream>>>(x, WG, BG, GATE);
  k_proj<<<dim3(64,5,16), 256, 0, stream>>>(x, WPh, WPl, BP, GATE, VDW, QSB, KET);
  k_energy<<<dim3(4,4,16), 256, 0, stream>>>(VDW, QSB, EN);
  k_softmax<<<2048, 256, 0, stream>>>(EN, ATT);
  k_out<<<dim3(64,16), 256, 0, stream>>>(x, ATT, KET, out);
}

// Round 3
// 363.123 us; speedup vs baseline: 1.3473x; 1.3473x over previous
//
#include <hip/hip_runtime.h>

#define BATCH 16
#define CIN 512
#define NPIX 4096

typedef __attribute__((ext_vector_type(8))) short bf16x8;
typedef __attribute__((ext_vector_type(4))) float f32x4;

#define MFMA(a,b,c) __builtin_amdgcn_mfma_f32_16x16x32_bf16((a),(b),(c),0,0,0)

union PK  { short s[8]; bf16x8 v; };
union PK4 { short s[4]; uint2 u; };

__device__ __forceinline__ unsigned short bf16_rne(float f){
  unsigned u = __float_as_uint(f);
  return (unsigned short)((u + 0x7fffu + ((u >> 16) & 1u)) >> 16);
}
__device__ __forceinline__ void f32_split(float f, short &h, short &l){
  unsigned short hu = bf16_rne(f);
  h = (short)hu;
  float fh = __uint_as_float((unsigned)hu << 16);
  l = (short)bf16_rne(f - fh);
}
__device__ __forceinline__ void split8(float4 a, float4 b, bf16x8 &h, bf16x8 &l){
  float vv[8] = {a.x,a.y,a.z,a.w,b.x,b.y,b.z,b.w};
  PK ph, pl;
  #pragma unroll
  for (int z=0;z<8;z++){ short hh,ll; f32_split(vv[z],hh,ll); ph.s[z]=hh; pl.s[z]=ll; }
  h = ph.v; l = pl.v;
}

// ---------------- weight convert ----------------
// WG  [512][512] bf16: row 2o = Wq[o], 2o+1 = Wk[o]
// WSE [128][512] bf16: rows 0-63 Ws, 64-127 We ; WSL [64][512] lo of Ws
__global__ __launch_bounds__(256)
void k_convw(const float* __restrict__ Wq, const float* __restrict__ bq,
             const float* __restrict__ Wk, const float* __restrict__ bk,
             const float* __restrict__ Ws, const float* __restrict__ bs,
             const float* __restrict__ We, const float* __restrict__ be,
             short* __restrict__ WG, short* __restrict__ WSE, short* __restrict__ WSL,
             float* __restrict__ BG, float* __restrict__ BSE){
  int t = blockIdx.x*256 + threadIdx.x;
  if (t < 512*512){
    int r = t >> 9, c = t & 511, o = r >> 1;
    float v = (r & 1) ? Wk[o*512+c] : Wq[o*512+c];
    WG[t] = (short)bf16_rne(v);
  }
  if (t < 128*512){
    int r = t >> 9, c = t & 511;
    float v = (r < 64) ? Ws[r*512+c] : We[(r-64)*512+c];
    short h,l; f32_split(v,h,l);
    WSE[t] = h;
    if (r < 64) WSL[t] = l;
  }
  if (t < 512) BG[t] = (t&1) ? bk[t>>1] : bq[t>>1];
  if (t < 128) BSE[t] = (t < 64) ? bs[t] : be[t-64];
}

// ---------------- x transpose: XT[b][n][c] bf16, LINEAR ----------------
__global__ __launch_bounds__(256)
void k_xt(const float* __restrict__ x, short* __restrict__ XT){
  __shared__ float XF[64*65];
  int cb = blockIdx.x, nb = blockIdx.y, b = blockIdx.z;
  int tid = threadIdx.x;
  {
    int cc = tid >> 2, ni = (tid & 3) * 16;
    const float* xp = x + ((size_t)(b*CIN + cb*64 + cc))*NPIX + nb*64 + ni;
    #pragma unroll
    for (int u=0;u<16;u+=4){
      float4 v = *(const float4*)(xp + u);
      XF[cc*65 + ni+u+0] = v.x; XF[cc*65 + ni+u+1] = v.y;
      XF[cc*65 + ni+u+2] = v.z; XF[cc*65 + ni+u+3] = v.w;
    }
  }
  __syncthreads();
  {
    int nn = tid & 63, cg = (tid >> 6) * 16;
    int n = nb*64 + nn;
    PK c0, c1;
    #pragma unroll
    for (int i=0;i<8;i++) c0.s[i] = (short)bf16_rne(XF[(cg+i)*65 + nn]);
    #pragma unroll
    for (int i=0;i<8;i++) c1.s[i] = (short)bf16_rne(XF[(cg+8+i)*65 + nn]);
    short* dst = XT + ((size_t)(b*NPIX + n))*512 + cb*64 + cg;
    *(bf16x8*)&dst[0] = c0.v;
    *(bf16x8*)&dst[8] = c1.v;
  }
}

// ---------------- gate: sigmoid(mean(Q*K)), fragments direct from global ----------------
__global__ __launch_bounds__(512)
void k_gate(const short* __restrict__ XT, const short* __restrict__ WG,
            const float* __restrict__ BG, float* __restrict__ GATE){
  __shared__ float QKf[512];
  int nt = blockIdx.x, b = blockIdx.y;
  int n0 = nt*64;
  int tid = threadIdx.x, w = tid>>6, lane = tid&63;
  int lr = lane&15, lk = (lane>>4)<<3;
  const short* wbase = WG + (size_t)(w*64 + lr)*512 + lk;
  const short* xbase = XT + ((size_t)(b*NPIX + n0))*512 + lk;
  f32x4 acc[4][4] = {};
  for (int kt=0; kt<16; kt++){
    bf16x8 av[4];
    #pragma unroll
    for (int r=0;r<4;r++) av[r] = *(const bf16x8*)(wbase + r*16*512 + kt*32);
    bf16x8 bb[4];
    #pragma unroll
    for (int j=0;j<4;j++) bb[j] = *(const bf16x8*)(xbase + (size_t)(j*16+lr)*512 + kt*32);
    #pragma unroll
    for (int r=0;r<4;r++)
      #pragma unroll
      for (int j=0;j<4;j++)
        acc[r][j] = MFMA(av[r], bb[j], acc[r][j]);
  }
  float p[4] = {0.f,0.f,0.f,0.f};
  int rq = (lane>>4)<<2;
  #pragma unroll
  for (int r=0;r<4;r++){
    f32x4 bg = *(const f32x4*)&BG[w*64 + r*16 + rq];
    #pragma unroll
    for (int j=0;j<4;j++){
      f32x4 a4 = acc[r][j];
      p[j] += (a4[0]+bg[0])*(a4[1]+bg[1]) + (a4[2]+bg[2])*(a4[3]+bg[3]);
    }
  }
  #pragma unroll
  for (int j=0;j<4;j++){ p[j] += __shfl_xor(p[j],16); p[j] += __shfl_xor(p[j],32); }
  if (lane < 16){
    #pragma unroll
    for (int j=0;j<4;j++) QKf[w*64 + j*16 + lane] = p[j];
  }
  __syncthreads();
  if (tid < 64){
    float s = 0.f;
    #pragma unroll
    for (int ww=0;ww<8;ww++) s += QKf[ww*64 + tid];
    GATE[(size_t)b*NPIX + n0 + tid] = 1.f/(1.f + __expf(-s*(1.f/256.f)));
  }
}

// ---------------- Qs (split, gate-folded) + Ke projections ----------------
__global__ __launch_bounds__(256)
void k_qske(const short* __restrict__ XT, const short* __restrict__ WSE,
            const short* __restrict__ WSL, const float* __restrict__ BSE,
            const float* __restrict__ GATE, float* __restrict__ QSG,
            short* __restrict__ KET, float* __restrict__ S){
  int nt = blockIdx.x, b = blockIdx.y;
  int n0 = nt*128;
  int tid = threadIdx.x, w = tid>>6, lane = tid&63;
  int lr = lane&15, lk = (lane>>4)<<3;
  bool isQs = (w < 2);
  const short* wb  = WSE + (size_t)(w*32 + lr)*512 + lk;
  const short* wlb = WSL + (size_t)((w&1)*32 + lr)*512 + lk;   // valid rows only
  f32x4 acc[2][8] = {};
  for (int kt=0; kt<16; kt++){
    bf16x8 ah[2], al[2];
    #pragma unroll
    for (int r=0;r<2;r++){
      ah[r] = *(const bf16x8*)(wb + r*16*512 + kt*32);
      al[r] = *(const bf16x8*)(wlb + r*16*512 + kt*32);
    }
    #pragma unroll
    for (int j=0;j<8;j++){
      int n = n0 + j*16 + lr;
      bf16x8 bb = *(const bf16x8*)&XT[((size_t)(b*NPIX + n))*512 + kt*32 + lk];
      #pragma unroll
      for (int r=0;r<2;r++){
        if (isQs) acc[r][j] = MFMA(al[r], bb, acc[r][j]);
        acc[r][j] = MFMA(ah[r], bb, acc[r][j]);
      }
    }
  }
  int rq = (lane>>4)<<2;
  if (isQs){
    float srow[2][4] = {{0.f,0.f,0.f,0.f},{0.f,0.f,0.f,0.f}};
    #pragma unroll
    for (int r=0;r<2;r++){
      int row = w*32 + r*16 + rq;
      f32x4 bs4 = *(const f32x4*)&BSE[row];
      #pragma unroll
      for (int j=0;j<8;j++){
        int n = n0 + j*16 + lr;
        float g = GATE[(size_t)b*NPIX + n];
        #pragma unroll
        for (int q=0;q<4;q++){
          float v = (acc[r][j][q] + bs4[q]) * g;
          QSG[((size_t)(b*64) + row + q)*NPIX + n] = v;
          srow[r][q] += v;
        }
      }
    }
    #pragma unroll
    for (int r=0;r<2;r++)
      #pragma unroll
      for (int q=0;q<4;q++){
        float v = srow[r][q];
        v += __shfl_xor(v,1); v += __shfl_xor(v,2);
        v += __shfl_xor(v,4); v += __shfl_xor(v,8);
        if (lr == 0) atomicAdd(&S[b*64 + w*32 + r*16 + rq + q], v);
      }
  } else {
    #pragma unroll
    for (int r=0;r<2;r++){
      int row = w*32 + r*16 + rq;          // 64..127 -> Ke d = row-64
      f32x4 be4 = *(const f32x4*)&BSE[row];
      int d = row - 64;
      #pragma unroll
      for (int j=0;j<8;j++){
        int n = n0 + j*16 + lr;
        PK4 pk;
        #pragma unroll
        for (int q=0;q<4;q++) pk.s[q] = (short)bf16_rne(acc[r][j][q] + be4[q]);
        *(uint2*)&KET[((size_t)(b*NPIX) + n)*64 + d] = pk.u;
      }
    }
  }
}

// ---------------- M[b][512][64] += x . QSG^T over n (reg-split, no LDS) ----------------
__global__ __launch_bounds__(512)
void k_M(const float* __restrict__ x, const float* __restrict__ QSG,
         float* __restrict__ M){
  int slab = blockIdx.x, b = blockIdx.y;
  int tid = threadIdx.x, w = tid>>6, lane = tid&63;
  int lr = lane&15, lk8 = (lane>>4)<<3;
  f32x4 acc[4][4] = {};
  for (int kt=0; kt<8; kt++){
    int noff = slab*256 + kt*32 + lk8;
    bf16x8 bh[4], bl[4];
    #pragma unroll
    for (int j=0;j<4;j++){
      const float* qp = QSG + ((size_t)(b*64) + j*16 + lr)*NPIX + noff;
      split8(*(const float4*)qp, *(const float4*)(qp+4), bh[j], bl[j]);
    }
    #pragma unroll
    for (int r=0;r<4;r++){
      const float* xp = x + ((size_t)(b*CIN) + w*64 + r*16 + lr)*NPIX + noff;
      bf16x8 ah, al;
      split8(*(const float4*)xp, *(const float4*)(xp+4), ah, al);
      #pragma unroll
      for (int j=0;j<4;j++){
        acc[r][j] = MFMA(al, bh[j], acc[r][j]);
        acc[r][j] = MFMA(ah, bl[j], acc[r][j]);
        acc[r][j] = MFMA(ah, bh[j], acc[r][j]);
      }
    }
  }
  int rq = (lane>>4)<<2;
  #pragma unroll
  for (int r=0;r<4;r++)
    #pragma unroll
    for (int j=0;j<4;j++)
      #pragma unroll
      for (int q=0;q<4;q++)
        atomicAdd(&M[((size_t)(b*CIN) + w*64 + r*16 + rq + q)*64 + j*16 + lr], acc[r][j][q]);
}

// ---------------- energy = Wv(f32) . M + bv*S  (VALU, exact) ----------------
__global__ __launch_bounds__(256)
void k_energy(const float* __restrict__ Wv, const float* __restrict__ bv,
              const float* __restrict__ M, const float* __restrict__ S,
              float* __restrict__ EN){
  __shared__ __align__(16) float ML[128*68];
  int cch = blockIdx.x, b = blockIdx.y;
  int tid = threadIdx.x;
  int d4 = tid & 15, ci = tid >> 4;
  f32x4 acc[2] = {};
  for (int kt=0; kt<4; kt++){
    __syncthreads();
    for (int i = tid; i < 2048; i += 256){
      int k = i >> 4, c4 = (i & 15) * 4;
      *(float4*)&ML[k*68 + c4] = *(const float4*)&M[((size_t)(b*CIN) + kt*128 + k)*64 + c4];
    }
    __syncthreads();
    #pragma unroll
    for (int m=0;m<2;m++){
      int c = cch*32 + ci + 16*m;
      const float* wvp = Wv + (size_t)c*512 + kt*128;
      for (int k4=0;k4<32;k4++){
        float4 wv4 = *(const float4*)(wvp + k4*4);
        f32x4 m0 = *(const f32x4*)&ML[(k4*4+0)*68 + d4*4];
        f32x4 m1 = *(const f32x4*)&ML[(k4*4+1)*68 + d4*4];
        f32x4 m2 = *(const f32x4*)&ML[(k4*4+2)*68 + d4*4];
        f32x4 m3 = *(const f32x4*)&ML[(k4*4+3)*68 + d4*4];
        acc[m] += m0*wv4.x + m1*wv4.y + m2*wv4.z + m3*wv4.w;
      }
    }
  }
  f32x4 s4 = *(const f32x4*)&S[b*64 + d4*4];
  #pragma unroll
  for (int m=0;m<2;m++){
    int c = cch*32 + ci + 16*m;
    f32x4 r = acc[m] + s4*bv[c];
    *(f32x4*)&EN[((size_t)(b*CIN) + c)*64 + d4*4] = r;
  }
}

// ---------------- softmax over d=64 ----------------
__global__ __launch_bounds__(256)
void k_softmax(const float* __restrict__ EN, short* __restrict__ ATT){
  int row = blockIdx.x*4 + (threadIdx.x>>6);
  int lane = threadIdx.x & 63;
  float v = EN[(size_t)row*64 + lane];
  float m = v;
  #pragma unroll
  for (int s=1;s<64;s<<=1) m = fmaxf(m, __shfl_xor(m, s));
  float e = __expf(v - m);
  float sum = e;
  #pragma unroll
  for (int s=1;s<64;s<<=1) sum += __shfl_xor(sum, s);
  ATT[(size_t)row*64 + lane] = (short)bf16_rne(e / sum);
}

// ---------------- out = x + attn . Ke ----------------
__global__ __launch_bounds__(512)
void k_out(const float* __restrict__ x, const short* __restrict__ ATT,
           const short* __restrict__ KET, float* __restrict__ out){
  int nt = blockIdx.x, b = blockIdx.y;
  int n0 = nt*64;
  int tid = threadIdx.x, w = tid>>6, lane = tid&63;
  int lr = lane&15, lk = (lane>>4)<<3;
  f32x4 acc[4][4] = {};
  #pragma unroll
  for (int kt=0; kt<2; kt++){
    bf16x8 bb[4];
    #pragma unroll
    for (int j=0;j<4;j++)
      bb[j] = *(const bf16x8*)&KET[((size_t)(b*NPIX) + n0 + j*16 + lr)*64 + kt*32 + lk];
    #pragma unroll
    for (int r=0;r<4;r++){
      bf16x8 a = *(const bf16x8*)&ATT[((size_t)(b*CIN) + w*64 + r*16 + lr)*64 + kt*32 + lk];
      #pragma unroll
      for (int j=0;j<4;j++)
        acc[r][j] = MFMA(a, bb[j], acc[r][j]);
    }
  }
  int rq = (lane>>4)<<2;
  #pragma unroll
  for (int r=0;r<4;r++)
    #pragma unroll
    for (int j=0;j<4;j++){
      int col = n0 + j*16 + lr;
      #pragma unroll
      for (int q=0;q<4;q++){
        size_t idx = ((size_t)(b*CIN) + w*64 + r*16 + rq + q)*NPIX + col;
        out[idx] = x[idx] + acc[r][j][q];
      }
    }
}

extern "C" void kernel_launch(void* const* d_in, const int* in_sizes, int n_in,
                              void* d_out, int out_size, void* d_ws, size_t ws_size,
                              hipStream_t stream){
  const float* x   = (const float*)d_in[0];
  const float* Wq  = (const float*)d_in[1];
  const float* bq  = (const float*)d_in[2];
  const float* Wk  = (const float*)d_in[3];
  const float* bk  = (const float*)d_in[4];
  const float* Wv  = (const float*)d_in[5];
  const float* bv  = (const float*)d_in[6];
  const float* Wsq = (const float*)d_in[7];
  const float* bsq = (const float*)d_in[8];
  const float* We  = (const float*)d_in[9];
  const float* be  = (const float*)d_in[10];
  float* out = (float*)d_out;

  char* wsb = (char*)d_ws;
  size_t off = 0;
  auto alloc = [&](size_t bytes)->void*{
    void* p = wsb + off; off += (bytes + 255) & ~(size_t)255; return p;
  };
  short* WG  = (short*)alloc((size_t)512*512*2);
  short* WSE = (short*)alloc((size_t)128*512*2);
  short* WSL = (short*)alloc((size_t)64*512*2);
  float* BG  = (float*)alloc(512*4);
  float* BSE = (float*)alloc(128*4);
  short* XT  = (short*)alloc((size_t)BATCH*NPIX*512*2);
  float* GATE= (float*)alloc((size_t)BATCH*NPIX*4);
  float* QSG = (float*)alloc((size_t)BATCH*64*NPIX*4);
  short* KET = (short*)alloc((size_t)BATCH*NPIX*64*2);
  float* Mb  = (float*)alloc((size_t)BATCH*512*64*4);
  float* Sb  = (float*)alloc((size_t)BATCH*64*4);
  float* EN  = (float*)alloc((size_t)BATCH*512*64*4);
  short* ATT = (short*)alloc((size_t)BATCH*512*64*2);

  hipMemsetAsync(Mb, 0, (size_t)BATCH*512*64*4, stream);
  hipMemsetAsync(Sb, 0, (size_t)BATCH*64*4, stream);

  k_convw  <<<1024, 256, 0, stream>>>(Wq,bq,Wk,bk,Wsq,bsq,We,be, WG,WSE,WSL,BG,BSE);
  k_xt     <<<dim3(8,64,16), 256, 0, stream>>>(x, XT);
  k_gate   <<<dim3(64,16), 512, 0, stream>>>(XT, WG, BG, GATE);
  k_qske   <<<dim3(32,16), 256, 0, stream>>>(XT, WSE, WSL, BSE, GATE, QSG, KET, Sb);
  k_M      <<<dim3(16,16), 512, 0, stream>>>(x, QSG, Mb);
  k_energy <<<dim3(16,16), 256, 0, stream>>>(Wv, bv, Mb, Sb, EN);
  k_softmax<<<2048, 256, 0, stream>>>(EN, ATT);
  k_out    <<<dim3(64,16), 512, 0, stream>>>(x, ATT, KET, out);
}

// Round 4
// 278.881 us; speedup vs baseline: 1.7542x; 1.3021x over previous
//
#include <hip/hip_runtime.h>

#define BATCH 16
#define CIN 512
#define NPIX 4096

typedef __attribute__((ext_vector_type(8))) short bf16x8;
typedef __attribute__((ext_vector_type(4))) float f32x4;

#define MFMA(a,b,c) __builtin_amdgcn_mfma_f32_16x16x32_bf16((a),(b),(c),0,0,0)

union PK  { short s[8]; bf16x8 v; };
union PK4 { short s[4]; uint2 u; };

__device__ __forceinline__ unsigned short bf16_rne(float f){
  unsigned u = __float_as_uint(f);
  return (unsigned short)((u + 0x7fffu + ((u >> 16) & 1u)) >> 16);
}
__device__ __forceinline__ void f32_split(float f, short &h, short &l){
  unsigned short hu = bf16_rne(f);
  h = (short)hu;
  float fh = __uint_as_float((unsigned)hu << 16);
  l = (short)bf16_rne(f - fh);
}
__device__ __forceinline__ void split8(float4 a, float4 b, bf16x8 &h, bf16x8 &l){
  float vv[8] = {a.x,a.y,a.z,a.w,b.x,b.y,b.z,b.w};
  PK ph, pl;
  #pragma unroll
  for (int z=0;z<8;z++){ short hh,ll; f32_split(vv[z],hh,ll); ph.s[z]=hh; pl.s[z]=ll; }
  h = ph.v; l = pl.v;
}

// chunk-XOR swizzle within a 512-short row (proven R1): (row,k) -> row*512 + slot*8 + (k&7)
__device__ __forceinline__ int offBig(int row, int k){
  int s = k >> 3;
  s = (s & ~7) | ((s ^ row) & 7);
  return row*512 + s*8 + (k & 7);
}

// ---------------- weight convert ----------------
// WG  [512][512] bf16: row 2o = Wq[o], 2o+1 = Wk[o]
// WSE [128][512] bf16: rows 0-63 Ws, 64-127 We ; WSL [64][512] lo of Ws
__global__ __launch_bounds__(256)
void k_convw(const float* __restrict__ Wq, const float* __restrict__ bq,
             const float* __restrict__ Wk, const float* __restrict__ bk,
             const float* __restrict__ Ws, const float* __restrict__ bs,
             const float* __restrict__ We, const float* __restrict__ be,
             short* __restrict__ WG, short* __restrict__ WSE, short* __restrict__ WSL,
             float* __restrict__ BG, float* __restrict__ BSE){
  int t = blockIdx.x*256 + threadIdx.x;
  if (t < 512*512){
    int r = t >> 9, c = t & 511, o = r >> 1;
    float v = (r & 1) ? Wk[o*512+c] : Wq[o*512+c];
    WG[t] = (short)bf16_rne(v);
  }
  if (t < 128*512){
    int r = t >> 9, c = t & 511;
    float v = (r < 64) ? Ws[r*512+c] : We[(r-64)*512+c];
    short h,l; f32_split(v,h,l);
    WSE[t] = h;
    if (r < 64) WSL[t] = l;
  }
  if (t < 512) BG[t] = (t&1) ? bk[t>>1] : bq[t>>1];
  if (t < 128) BSE[t] = (t < 64) ? bs[t] : be[t-64];
}

// ---------------- fused front: gate + Qs(split,gate-folded) + Ke ----------------
// grid (64 nt, 16 b), 512 thr (8 waves). x staged once into swizzled LDS.
__global__ __launch_bounds__(512)
void k_front(const float* __restrict__ x, const short* __restrict__ WG,
             const float* __restrict__ BG, const short* __restrict__ WSE,
             const short* __restrict__ WSL, const float* __restrict__ BSE,
             float* __restrict__ QSG, short* __restrict__ KET, float* __restrict__ S){
  __shared__ __align__(16) short XS[64*512];   // [n][c] bf16-hi, chunk-swizzled
  __shared__ float QKf[512];
  __shared__ float GF[64];
  int nt = blockIdx.x, b = blockIdx.y;
  int n0 = nt*64;
  int tid = threadIdx.x, w = tid>>6, lane = tid&63;
  int lr = lane&15, lk = (lane>>4)<<3;

  // stage: thread = channel c, transpose-write 64 n values (R1-proven)
  {
    const float* xp = x + ((size_t)b*CIN + tid)*NPIX + n0;
    for (int i=0;i<64;i+=4){
      float4 v = *(const float4*)(xp + i);
      float vv[4] = {v.x, v.y, v.z, v.w};
      #pragma unroll
      for (int u=0;u<4;u++)
        XS[offBig(i+u, tid)] = (short)bf16_rne(vv[u]);
    }
  }
  __syncthreads();

  // ---- phase 1: gate GEMM (interleaved Q/K rows), A direct from global (L2) ----
  {
    const short* wbase = WG + (size_t)(w*64 + lr)*512 + lk;
    f32x4 acc[4][4] = {};
    for (int kt=0; kt<16; kt++){
      bf16x8 av[4];
      #pragma unroll
      for (int r=0;r<4;r++) av[r] = *(const bf16x8*)(wbase + r*16*512 + kt*32);
      bf16x8 bb[4];
      #pragma unroll
      for (int j=0;j<4;j++) bb[j] = *(const bf16x8*)&XS[offBig(j*16+lr, kt*32+lk)];
      #pragma unroll
      for (int r=0;r<4;r++)
        #pragma unroll
        for (int j=0;j<4;j++)
          acc[r][j] = MFMA(av[r], bb[j], acc[r][j]);
    }
    float p[4] = {0.f,0.f,0.f,0.f};
    int rq = (lane>>4)<<2;
    #pragma unroll
    for (int r=0;r<4;r++){
      f32x4 bg = *(const f32x4*)&BG[w*64 + r*16 + rq];
      #pragma unroll
      for (int j=0;j<4;j++){
        f32x4 a4 = acc[r][j];
        p[j] += (a4[0]+bg[0])*(a4[1]+bg[1]) + (a4[2]+bg[2])*(a4[3]+bg[3]);
      }
    }
    #pragma unroll
    for (int j=0;j<4;j++){ p[j] += __shfl_xor(p[j],16); p[j] += __shfl_xor(p[j],32); }
    if (lane < 16){
      #pragma unroll
      for (int j=0;j<4;j++) QKf[w*64 + j*16 + lane] = p[j];
    }
  }
  __syncthreads();
  if (tid < 64){
    float s = 0.f;
    #pragma unroll
    for (int ww=0;ww<8;ww++) s += QKf[ww*64 + tid];
    GF[tid] = 1.f/(1.f + __expf(-s*(1.f/256.f)));
  }
  __syncthreads();

  // ---- phase 2: Qs (waves 0-3, hi+lo) and Ke (waves 4-7) ----
  bool isQs = (w < 4);
  int arow = isQs ? (w*16 + lr) : (64 + (w-4)*16 + lr);
  const short* wb  = WSE + (size_t)arow*512 + lk;
  const short* wlb = WSL + (size_t)(isQs ? (w*16 + lr) : 0)*512 + lk;
  f32x4 acc2[4] = {};
  for (int kt=0; kt<16; kt++){
    bf16x8 bb[4];
    #pragma unroll
    for (int j=0;j<4;j++) bb[j] = *(const bf16x8*)&XS[offBig(j*16+lr, kt*32+lk)];
    bf16x8 ah = *(const bf16x8*)(wb + kt*32);
    if (isQs){
      bf16x8 al = *(const bf16x8*)(wlb + kt*32);
      #pragma unroll
      for (int j=0;j<4;j++){
        acc2[j] = MFMA(al, bb[j], acc2[j]);
        acc2[j] = MFMA(ah, bb[j], acc2[j]);
      }
    } else {
      #pragma unroll
      for (int j=0;j<4;j++)
        acc2[j] = MFMA(ah, bb[j], acc2[j]);
    }
  }
  int rq = (lane>>4)<<2;
  if (isQs){
    int row0 = w*16 + rq;
    f32x4 bs4 = *(const f32x4*)&BSE[row0];
    float srow[4] = {0.f,0.f,0.f,0.f};
    #pragma unroll
    for (int j=0;j<4;j++){
      int nl = j*16 + lr;
      float g = GF[nl];
      int n = n0 + nl;
      #pragma unroll
      for (int q=0;q<4;q++){
        float v = (acc2[j][q] + bs4[q]) * g;
        QSG[((size_t)(b*64) + row0 + q)*NPIX + n] = v;
        srow[q] += v;
      }
    }
    #pragma unroll
    for (int q=0;q<4;q++){
      float v = srow[q];
      v += __shfl_xor(v,1); v += __shfl_xor(v,2);
      v += __shfl_xor(v,4); v += __shfl_xor(v,8);
      if (lr == 0) atomicAdd(&S[b*64 + row0 + q], v);
    }
  } else {
    int d0 = (w-4)*16 + rq;
    f32x4 be4 = *(const f32x4*)&BSE[64 + d0];
    #pragma unroll
    for (int j=0;j<4;j++){
      int n = n0 + j*16 + lr;
      PK4 pk;
      #pragma unroll
      for (int q=0;q<4;q++) pk.s[q] = (short)bf16_rne(acc2[j][q] + be4[q]);
      *(uint2*)&KET[((size_t)(b*NPIX) + n)*64 + d0] = pk.u;
    }
  }
}

// ---------------- M[b][512][64] += x . QSG^T over n (reg-split, no LDS) ----------------
__global__ __launch_bounds__(512)
void k_M(const float* __restrict__ x, const float* __restrict__ QSG,
         float* __restrict__ M){
  int slab = blockIdx.x, b = blockIdx.y;
  int tid = threadIdx.x, w = tid>>6, lane = tid&63;
  int lr = lane&15, lk8 = (lane>>4)<<3;
  f32x4 acc[4][4] = {};
  for (int kt=0; kt<8; kt++){
    int noff = slab*256 + kt*32 + lk8;
    bf16x8 bh[4], bl[4];
    #pragma unroll
    for (int j=0;j<4;j++){
      const float* qp = QSG + ((size_t)(b*64) + j*16 + lr)*NPIX + noff;
      split8(*(const float4*)qp, *(const float4*)(qp+4), bh[j], bl[j]);
    }
    #pragma unroll
    for (int r=0;r<4;r++){
      const float* xp = x + ((size_t)(b*CIN) + w*64 + r*16 + lr)*NPIX + noff;
      bf16x8 ah, al;
      split8(*(const float4*)xp, *(const float4*)(xp+4), ah, al);
      #pragma unroll
      for (int j=0;j<4;j++){
        acc[r][j] = MFMA(al, bh[j], acc[r][j]);
        acc[r][j] = MFMA(ah, bl[j], acc[r][j]);
        acc[r][j] = MFMA(ah, bh[j], acc[r][j]);
      }
    }
  }
  int rq = (lane>>4)<<2;
  #pragma unroll
  for (int r=0;r<4;r++)
    #pragma unroll
    for (int j=0;j<4;j++)
      #pragma unroll
      for (int q=0;q<4;q++)
        atomicAdd(&M[((size_t)(b*CIN) + w*64 + r*16 + rq + q)*64 + j*16 + lr], acc[r][j][q]);
}

// ---------------- energy = Wv(f32) . M + bv*S  (VALU, exact) ----------------
__global__ __launch_bounds__(256)
void k_energy(const float* __restrict__ Wv, const float* __restrict__ bv,
              const float* __restrict__ M, const float* __restrict__ S,
              float* __restrict__ EN){
  __shared__ __align__(16) float ML[128*68];
  int cch = blockIdx.x, b = blockIdx.y;
  int tid = threadIdx.x;
  int d4 = tid & 15, ci = tid >> 4;
  f32x4 acc[2] = {};
  for (int kt=0; kt<4; kt++){
    __syncthreads();
    for (int i = tid; i < 2048; i += 256){
      int k = i >> 4, c4 = (i & 15) * 4;
      *(float4*)&ML[k*68 + c4] = *(const float4*)&M[((size_t)(b*CIN) + kt*128 + k)*64 + c4];
    }
    __syncthreads();
    #pragma unroll
    for (int m=0;m<2;m++){
      int c = cch*32 + ci + 16*m;
      const float* wvp = Wv + (size_t)c*512 + kt*128;
      for (int k4=0;k4<32;k4++){
        float4 wv4 = *(const float4*)(wvp + k4*4);
        f32x4 m0 = *(const f32x4*)&ML[(k4*4+0)*68 + d4*4];
        f32x4 m1 = *(const f32x4*)&ML[(k4*4+1)*68 + d4*4];
        f32x4 m2 = *(const f32x4*)&ML[(k4*4+2)*68 + d4*4];
        f32x4 m3 = *(const f32x4*)&ML[(k4*4+3)*68 + d4*4];
        acc[m] += m0*wv4.x + m1*wv4.y + m2*wv4.z + m3*wv4.w;
      }
    }
  }
  f32x4 s4 = *(const f32x4*)&S[b*64 + d4*4];
  #pragma unroll
  for (int m=0;m<2;m++){
    int c = cch*32 + ci + 16*m;
    f32x4 r = acc[m] + s4*bv[c];
    *(f32x4*)&EN[((size_t)(b*CIN) + c)*64 + d4*4] = r;
  }
}

// ---------------- softmax over d=64 ----------------
__global__ __launch_bounds__(256)
void k_softmax(const float* __restrict__ EN, short* __restrict__ ATT){
  int row = blockIdx.x*4 + (threadIdx.x>>6);
  int lane = threadIdx.x & 63;
  float v = EN[(size_t)row*64 + lane];
  float m = v;
  #pragma unroll
  for (int s=1;s<64;s<<=1) m = fmaxf(m, __shfl_xor(m, s));
  float e = __expf(v - m);
  float sum = e;
  #pragma unroll
  for (int s=1;s<64;s<<=1) sum += __shfl_xor(sum, s);
  ATT[(size_t)row*64 + lane] = (short)bf16_rne(e / sum);
}

// ---------------- out = x + attn . Ke ----------------
__global__ __launch_bounds__(512)
void k_out(const float* __restrict__ x, const short* __restrict__ ATT,
           const short* __restrict__ KET, float* __restrict__ out){
  int nt = blockIdx.x, b = blockIdx.y;
  int n0 = nt*64;
  int tid = threadIdx.x, w = tid>>6, lane = tid&63;
  int lr = lane&15, lk = (lane>>4)<<3;
  f32x4 acc[4][4] = {};
  #pragma unroll
  for (int kt=0; kt<2; kt++){
    bf16x8 bb[4];
    #pragma unroll
    for (int j=0;j<4;j++)
      bb[j] = *(const bf16x8*)&KET[((size_t)(b*NPIX) + n0 + j*16 + lr)*64 + kt*32 + lk];
    #pragma unroll
    for (int r=0;r<4;r++){
      bf16x8 a = *(const bf16x8*)&ATT[((size_t)(b*CIN) + w*64 + r*16 + lr)*64 + kt*32 + lk];
      #pragma unroll
      for (int j=0;j<4;j++)
        acc[r][j] = MFMA(a, bb[j], acc[r][j]);
    }
  }
  int rq = (lane>>4)<<2;
  #pragma unroll
  for (int r=0;r<4;r++)
    #pragma unroll
    for (int j=0;j<4;j++){
      int col = n0 + j*16 + lr;
      #pragma unroll
      for (int q=0;q<4;q++){
        size_t idx = ((size_t)(b*CIN) + w*64 + r*16 + rq + q)*NPIX + col;
        out[idx] = x[idx] + acc[r][j][q];
      }
    }
}

extern "C" void kernel_launch(void* const* d_in, const int* in_sizes, int n_in,
                              void* d_out, int out_size, void* d_ws, size_t ws_size,
                              hipStream_t stream){
  const float* x   = (const float*)d_in[0];
  const float* Wq  = (const float*)d_in[1];
  const float* bq  = (const float*)d_in[2];
  const float* Wk  = (const float*)d_in[3];
  const float* bk  = (const float*)d_in[4];
  const float* Wv  = (const float*)d_in[5];
  const float* bv  = (const float*)d_in[6];
  const float* Wsq = (const float*)d_in[7];
  const float* bsq = (const float*)d_in[8];
  const float* We  = (const float*)d_in[9];
  const float* be  = (const float*)d_in[10];
  float* out = (float*)d_out;

  char* wsb = (char*)d_ws;
  size_t off = 0;
  auto alloc = [&](size_t bytes)->void*{
    void* p = wsb + off; off += (bytes + 255) & ~(size_t)255; return p;
  };
  short* WG  = (short*)alloc((size_t)512*512*2);
  short* WSE = (short*)alloc((size_t)128*512*2);
  short* WSL = (short*)alloc((size_t)64*512*2);
  float* BG  = (float*)alloc(512*4);
  float* BSE = (float*)alloc(128*4);
  float* QSG = (float*)alloc((size_t)BATCH*64*NPIX*4);
  short* KET = (short*)alloc((size_t)BATCH*NPIX*64*2);
  float* Mb  = (float*)alloc((size_t)BATCH*512*64*4);
  float* Sb  = (float*)alloc((size_t)BATCH*64*4);
  float* EN  = (float*)alloc((size_t)BATCH*512*64*4);
  short* ATT = (short*)alloc((size_t)BATCH*512*64*2);

  hipMemsetAsync(Mb, 0, (size_t)BATCH*512*64*4, stream);
  hipMemsetAsync(Sb, 0, (size_t)BATCH*64*4, stream);

  k_convw  <<<1024, 256, 0, stream>>>(Wq,bq,Wk,bk,Wsq,bsq,We,be, WG,WSE,WSL,BG,BSE);
  k_front  <<<dim3(64,16), 512, 0, stream>>>(x, WG, BG, WSE, WSL, BSE, QSG, KET, Sb);
  k_M      <<<dim3(16,16), 512, 0, stream>>>(x, QSG, Mb);
  k_energy <<<dim3(16,16), 256, 0, stream>>>(Wv, bv, Mb, Sb, EN);
  k_softmax<<<2048, 256, 0, stream>>>(EN, ATT);
  k_out    <<<dim3(64,16), 512, 0, stream>>>(x, ATT, KET, out);
}